// Round 6
// baseline (375.089 us; speedup 1.0000x reference)
//
#include <hip/hip_runtime.h>
#include <hip/hip_bf16.h>

// WorkflowGNN: GCN(32->64)+ReLU, GAT(64->64,h=1)+ReLU, GCN(64->64)+ReLU,
// heads: opt [N,10], bottleneck [N,1], mean-embed [64]. f32 in/out.
// R21b: node-per-wave agg (lane=feature) WITHOUT variable-index readlane
// (suspected compile failure in R21). Neighbor indices come from SCALAR
// loads of the uniform adj row (s_load_dwordx4 via uniformity analysis);
// GAT edge weight recomputed scalarly from als[u] (bit-identical ops) --
// zero cross-lane ops in the gather loop. Row gather = 1 coalesced 128B
// u16 load; no butterfly over features. 4-wide unroll for MLP.
// R20 (kept): k_agg32g epilogue broadcasts via constant-index v_readlane.
// R19 (kept): atomic-free adjacency build (k_part exact buckets + k_fill LDS).

#define CAP 64
#define NP2 128          // nodes per bucket (LDS tile rows), = 1<<7
#define NB2MAX 800       // LDS cursor array bound (n <= 102400)

__device__ __forceinline__ int uwave(){                 // wave id, known-uniform
  return __builtin_amdgcn_readfirstlane(threadIdx.x >> 6);
}
__device__ __forceinline__ unsigned short f2bf(float f){ // RNE, finite inputs
  unsigned u = __float_as_uint(f);
  return (unsigned short)((u + 0x7fffu + ((u >> 16) & 1u)) >> 16);
}
__device__ __forceinline__ float bfl(unsigned u){ return __uint_as_float(u << 16); }
__device__ __forceinline__ float bfh(unsigned u){ return __uint_as_float(u & 0xffff0000u); }
__device__ __forceinline__ float bfu(unsigned short s){ return __uint_as_float(((unsigned)s) << 16); }
__device__ __forceinline__ float rdlane(float v, int l){ // constant-lane broadcast (R20-proven)
  return __uint_as_float(__builtin_amdgcn_readlane(__float_as_uint(v), l));
}

// setup: zero bcnt/pad-rows/emb_acc, pack Wcat/bcat (cnt now written by k_fill)
__global__ void k_setup(const float* __restrict__ Wopt, const float* __restrict__ bopt,
                        const float* __restrict__ Wb1, const float* __restrict__ bb1,
                        float* __restrict__ Wcat, float* __restrict__ bcat,
                        int* __restrict__ bcnt, unsigned short* __restrict__ tb,
                        unsigned short* __restrict__ xh, float* __restrict__ emb_acc,
                        int n, int nb2){
  int i = blockIdx.x*blockDim.x + threadIdx.x;
  if (i < nb2) bcnt[i] = 0;
  if (blockIdx.x == 0){
    int tid = threadIdx.x;
    for (int j = tid; j < 4096; j += 256){    // pack head weights
      int f = j >> 6, c = j & 63;
      float w = 0.f;
      if (c < 10)       w = Wopt[f*10 + c];
      else if (c >= 32) w = Wb1[f*32 + (c-32)];
      Wcat[j] = w;
    }
    if (tid < 64){
      float b = 0.f;
      if (tid < 10)       b = bopt[tid];
      else if (tid >= 32) b = bb1[tid-32];
      bcat[tid] = b;
      tb[(size_t)n*64 + tid] = 0;             // zero pad row (64-feat)
      emb_acc[tid] = 0.f;
    }
    if (tid >= 64 && tid < 96) xh[(size_t)n*32 + (tid-64)] = 0;  // zero pad row (32-feat)
  }
}

// pass A: bin edges into exact dst-range buckets (bk = dst>>7). One coalesced
// read of src/dst (2x int4 each), LDS-aggregated cursors -> ~nb2 global
// atomics per block on 782 hot counters.
__global__ __launch_bounds__(256) void k_part(const int* __restrict__ src,
                        const int* __restrict__ dst,
                        uint2* __restrict__ pairs, int* __restrict__ bcnt,
                        int e, int nb2, int pbcap){
  __shared__ int lcnt[NB2MAX];
  __shared__ int lbase[NB2MAX];
  int tid = threadIdx.x;
  for (int j = tid; j < nb2; j += 256) lcnt[j] = 0;
  __syncthreads();
  int i0 = blockIdx.x*2048 + tid*8;
  int d[8], s[8], bk[8], lp[8];
  int nv = e - i0;
  if (nv > 8) nv = 8;
  if (nv < 0) nv = 0;
  if (nv == 8){
    int4 d0 = *(const int4*)(dst + i0), d1 = *(const int4*)(dst + i0 + 4);
    int4 s0 = *(const int4*)(src + i0), s1 = *(const int4*)(src + i0 + 4);
    d[0]=d0.x; d[1]=d0.y; d[2]=d0.z; d[3]=d0.w;
    d[4]=d1.x; d[5]=d1.y; d[6]=d1.z; d[7]=d1.w;
    s[0]=s0.x; s[1]=s0.y; s[2]=s0.z; s[3]=s0.w;
    s[4]=s1.x; s[5]=s1.y; s[6]=s1.z; s[7]=s1.w;
  } else {
    #pragma unroll
    for (int j = 0; j < 8; j++){ d[j] = 0; s[j] = 0; }
    for (int j = 0; j < nv; j++){ d[j] = dst[i0+j]; s[j] = src[i0+j]; }
  }
  #pragma unroll
  for (int j = 0; j < 8; j++){
    if (j < nv){
      bk[j] = d[j] >> 7;                      // exact: bucket owns [bk*128, bk*128+128)
      lp[j] = atomicAdd(&lcnt[bk[j]], 1);
    }
  }
  __syncthreads();
  for (int j = tid; j < nb2; j += 256){
    int c = lcnt[j];
    if (c) lbase[j] = atomicAdd(&bcnt[j], c);
  }
  __syncthreads();
  #pragma unroll
  for (int j = 0; j < 8; j++){
    if (j < nv){
      int p = lbase[bk[j]] + lp[j];
      if (p < pbcap)
        pairs[(size_t)bk[j]*pbcap + p] = make_uint2((unsigned)d[j], (unsigned)s[j]);
    }
  }
}

// pass B: one block per bucket. Build 128 adj rows in LDS (LDS atomics only,
// zero global atomics), then write rows + cnt fully coalesced. Slots beyond
// lc[r] are garbage -> never read downstream (lane < c guards).
__global__ __launch_bounds__(256) void k_fill(const uint2* __restrict__ pairs,
                        const int* __restrict__ bcnt, int* __restrict__ cnt,
                        int* __restrict__ adj, int pbcap, int n){
  __shared__ int lc[NP2];
  __shared__ int ladj[NP2*CAP];               // 32KB
  int b = blockIdx.x;
  int lo = b << 7;
  int nn = min(NP2, n - lo);
  int tid = threadIdx.x;
  for (int j = tid; j < NP2; j += 256) lc[j] = 0;
  __syncthreads();
  int m = bcnt[b];
  if (m > pbcap) m = pbcap;
  const uint2* pb = pairs + (size_t)b*pbcap;
  for (int j = tid; j < m; j += 256){
    uint2 p = pb[j];
    int r = (int)p.x - lo;
    int pos = atomicAdd(&lc[r], 1);
    if (pos < CAP) ladj[(r << 6) + pos] = (int)p.y;
  }
  __syncthreads();
  if (tid < nn) cnt[lo + tid] = lc[tid];
  int tot = nn << 4;                          // nn*64 ints / 4 per uint4
  uint4* ga = (uint4*)(adj + (size_t)lo*CAP);
  const uint4* la = (const uint4*)ladj;
  for (int j = tid; j < tot; j += 256) ga[j] = la[j];
}

// cast x -> bf16, pre-scaled by rsqrt(deg): xs[v] = x[v]*rsqrt(cnt[v]+1)
__global__ void k_castscale(const float* __restrict__ x, const int* __restrict__ cnt,
                            unsigned short* __restrict__ xh, int total4){
  int i = blockIdx.x*blockDim.x + threadIdx.x;
  if (i >= total4) return;
  int row = i >> 3;                           // 8 float4 per 32-elem row
  float dv = rsqrtf((float)(cnt[row] + 1));
  float4 v = ((const float4*)x)[i];
  uint2 o;
  o.x = (unsigned)f2bf(v.x*dv) | ((unsigned)f2bf(v.y*dv) << 16);
  o.y = (unsigned)f2bf(v.z*dv) | ((unsigned)f2bf(v.w*dv) << 16);
  ((uint2*)xh)[i] = o;
}

// layer-1 FUSED aggregate+gemm, DUAL-NODE, bf16 out.
// Epilogue broadcasts via v_readlane (VALU) instead of __shfl (DS pipe).
__global__ __launch_bounds__(256) void k_agg32g(const unsigned short* __restrict__ xh,
                          const int* __restrict__ adj, const int* __restrict__ cnt,
                          const float* __restrict__ W1, const float* __restrict__ b1,
                          unsigned short* __restrict__ h, int n){
  int lane = threadIdx.x & 63;
  float wreg[32];
  #pragma unroll
  for (int k = 0; k < 32; k++) wreg[k] = W1[k*64 + lane];  // coalesced, once
  float br = b1[lane];
  int v0 = blockIdx.x*8 + uwave()*2;
  if (v0 >= n) return;                        // uniform
  int v1 = v0 + 1;
  bool has1 = v1 < n;
  if (!has1) v1 = v0;
  int cn0 = cnt[v0], cn1 = cnt[v1];
  int c0 = min(cn0, CAP), c1 = min(cn1, CAP);
  int ureg0 = n, ureg1 = n;                   // pad -> zero row
  if (lane < c0) ureg0 = (adj + (size_t)v0*CAP)[lane];
  if (lane < c1) ureg1 = (adj + (size_t)v1*CAP)[lane];
  int g = lane >> 3, q = lane & 7;
  float4 a0 = {0.f,0.f,0.f,0.f}, a1 = {0.f,0.f,0.f,0.f};
  int itm = (max(c0, c1) + 7) >> 3;
  #pragma unroll 2
  for (int jj = 0; jj < itm; jj++){
    int u0 = __shfl(ureg0, jj*8 + g);         // pad iters -> zero row (L1-hot)
    int u1 = __shfl(ureg1, jj*8 + g);
    uint2 r0 = ((const uint2*)(xh + (size_t)u0*32))[q];   // both loads in flight
    uint2 r1 = ((const uint2*)(xh + (size_t)u1*32))[q];
    a0.x += bfl(r0.x); a0.y += bfh(r0.x); a0.z += bfl(r0.y); a0.w += bfh(r0.y);
    a1.x += bfl(r1.x); a1.y += bfh(r1.x); a1.z += bfl(r1.y); a1.w += bfh(r1.y);
  }
  #pragma unroll
  for (int off = 8; off <= 32; off <<= 1){
    a0.x += __shfl_xor(a0.x, off); a0.y += __shfl_xor(a0.y, off);
    a0.z += __shfl_xor(a0.z, off); a0.w += __shfl_xor(a0.w, off);
    a1.x += __shfl_xor(a1.x, off); a1.y += __shfl_xor(a1.y, off);
    a1.z += __shfl_xor(a1.z, off); a1.w += __shfl_xor(a1.w, off);
  }
  uint2 s0 = ((const uint2*)(xh + (size_t)v0*32))[q];     // self rows (pre-scaled)
  uint2 s1 = ((const uint2*)(xh + (size_t)v1*32))[q];
  a0.x += bfl(s0.x); a0.y += bfh(s0.x); a0.z += bfl(s0.y); a0.w += bfh(s0.y);
  a1.x += bfl(s1.x); a1.y += bfh(s1.x); a1.z += bfl(s1.y); a1.w += bfh(s1.y);
  float dv0 = rsqrtf((float)(cn0 + 1)), dv1 = rsqrtf((float)(cn1 + 1));
  a0.x *= dv0; a0.y *= dv0; a0.z *= dv0; a0.w *= dv0;
  a1.x *= dv1; a1.y *= dv1; a1.z *= dv1; a1.w *= dv1;
  float h0 = br, h1v = br;                    // epilogue gemms via v_readlane (VALU)
  #pragma unroll
  for (int q2 = 0; q2 < 8; q2++){
    float w0x = rdlane(a0.x, q2), w1x = rdlane(a1.x, q2);
    float w0y = rdlane(a0.y, q2), w1y = rdlane(a1.y, q2);
    float w0z = rdlane(a0.z, q2), w1z = rdlane(a1.z, q2);
    float w0w = rdlane(a0.w, q2), w1w = rdlane(a1.w, q2);
    h0 = fmaf(w0x, wreg[q2*4+0], h0); h1v = fmaf(w1x, wreg[q2*4+0], h1v);
    h0 = fmaf(w0y, wreg[q2*4+1], h0); h1v = fmaf(w1y, wreg[q2*4+1], h1v);
    h0 = fmaf(w0z, wreg[q2*4+2], h0); h1v = fmaf(w1z, wreg[q2*4+2], h1v);
    h0 = fmaf(w0w, wreg[q2*4+3], h0); h1v = fmaf(w1w, wreg[q2*4+3], h1v);
  }
  h[(size_t)v0*64 + lane] = f2bf(fmaxf(h0, 0.f));   // 128B coalesced
  if (has1) h[(size_t)v1*64 + lane] = f2bf(fmaxf(h1v, 0.f));
}

// K=64 GEMM (bf16 in) -> bf16 out, optional pre-scale by rsqrt(deg)
template<bool SCALE>
__global__ __launch_bounds__(256, 4) void k_gemm_b(const unsigned short* __restrict__ x,
                       const float* __restrict__ W, const int* __restrict__ cnt,
                       unsigned short* __restrict__ t, int n){
  int lane = threadIdx.x & 63;
  int gw = blockIdx.x*4 + uwave();
  int nw = gridDim.x*4;
  float wreg[64];
  #pragma unroll
  for (int k = 0; k < 64; k++) wreg[k] = W[k*64 + lane];
  for (int v = gw; v < n; v += nw){
    const uint4* xr = (const uint4*)(x + (size_t)v*64);   // uniform row, 8x16B
    float acc = 0.f;
    #pragma unroll
    for (int k8 = 0; k8 < 8; k8++){
      uint4 c = xr[k8];
      acc = fmaf(bfl(c.x), wreg[k8*8+0], acc);
      acc = fmaf(bfh(c.x), wreg[k8*8+1], acc);
      acc = fmaf(bfl(c.y), wreg[k8*8+2], acc);
      acc = fmaf(bfh(c.y), wreg[k8*8+3], acc);
      acc = fmaf(bfl(c.z), wreg[k8*8+4], acc);
      acc = fmaf(bfh(c.z), wreg[k8*8+5], acc);
      acc = fmaf(bfl(c.w), wreg[k8*8+6], acc);
      acc = fmaf(bfh(c.w), wreg[k8*8+7], acc);
    }
    if (SCALE) acc *= rsqrtf((float)(cnt[v] + 1));
    t[(size_t)v*64 + lane] = f2bf(acc);                    // 128B coalesced
  }
}

// K=64 GEMM (bf16 in) -> bf16 out + fused alpha_src/alpha_dst dots (f32 scores)
__global__ __launch_bounds__(256, 4) void k_gemm_alpha(const unsigned short* __restrict__ x,
                       const float* __restrict__ W,
                       const float* __restrict__ asrc, const float* __restrict__ adst,
                       unsigned short* __restrict__ t, float* __restrict__ als,
                       float* __restrict__ ald, int n){
  int lane = threadIdx.x & 63;
  int gw = blockIdx.x*4 + uwave();
  int nw = gridDim.x*4;
  float wreg[64];
  #pragma unroll
  for (int k = 0; k < 64; k++) wreg[k] = W[k*64 + lane];
  float asr = asrc[lane], adr = adst[lane];
  for (int v = gw; v < n; v += nw){
    const uint4* xr = (const uint4*)(x + (size_t)v*64);
    float acc = 0.f;
    #pragma unroll
    for (int k8 = 0; k8 < 8; k8++){
      uint4 c = xr[k8];
      acc = fmaf(bfl(c.x), wreg[k8*8+0], acc);
      acc = fmaf(bfh(c.x), wreg[k8*8+1], acc);
      acc = fmaf(bfl(c.y), wreg[k8*8+2], acc);
      acc = fmaf(bfh(c.y), wreg[k8*8+3], acc);
      acc = fmaf(bfl(c.z), wreg[k8*8+4], acc);
      acc = fmaf(bfh(c.z), wreg[k8*8+5], acc);
      acc = fmaf(bfl(c.w), wreg[k8*8+6], acc);
      acc = fmaf(bfh(c.w), wreg[k8*8+7], acc);
    }
    t[(size_t)v*64 + lane] = f2bf(acc);
    float s1 = acc * asr, s2 = acc * adr;
    #pragma unroll
    for (int off = 32; off; off >>= 1){
      s1 += __shfl_xor(s1, off);
      s2 += __shfl_xor(s2, off);
    }
    if (lane == 0){ als[v] = s1; ald[v] = s2; }
  }
}

// GCN agg (layer 3): ONE NODE PER WAVE, lane = feature. Neighbor indices via
// SCALAR loads of the uniform adj row (no cross-lane ops); coalesced 128B
// u16 row loads; 4-wide unroll keeps 4 loads in flight. No butterfly.
__global__ __launch_bounds__(256) void k_gcn_agg(const unsigned short* __restrict__ t,
                          const int* __restrict__ adj, const int* __restrict__ cnt,
                          const float* __restrict__ b, unsigned short* __restrict__ h, int n){
  int lane = threadIdx.x & 63;
  int v = blockIdx.x*4 + uwave();
  if (v >= n) return;                         // uniform
  int cn = cnt[v];                            // uniform -> scalar load
  int c = min(cn, CAP);
  const int* row = adj + (size_t)v*CAP;       // uniform base
  float acc = bfu(t[(size_t)v*64 + lane]);    // self row
  int j = 0;
  for (; j + 3 < c; j += 4){
    int u0 = row[j], u1 = row[j+1], u2 = row[j+2], u3 = row[j+3];  // s_load_dwordx4
    float x0 = bfu(t[(size_t)u0*64 + lane]);  // 4x 128B loads in flight
    float x1 = bfu(t[(size_t)u1*64 + lane]);
    float x2 = bfu(t[(size_t)u2*64 + lane]);
    float x3 = bfu(t[(size_t)u3*64 + lane]);
    acc += x0; acc += x1; acc += x2; acc += x3;
  }
  for (; j < c; j++){
    int u0 = row[j];
    acc += bfu(t[(size_t)u0*64 + lane]);
  }
  float dv = rsqrtf((float)(cn + 1));
  float out = fmaxf(fmaf(acc, dv, b[lane]), 0.f);
  h[(size_t)v*64 + lane] = f2bf(out);         // 128B coalesced
}

// GAT agg: ONE NODE PER WAVE, lane = feature. Wave softmax (12 shfl_xor once),
// then serial weighted gather: scalar-load u, RECOMPUTE w=exp(lrelu(als[u]+adv)-em)
// scalarly (bit-identical to lane-phase p) -- zero cross-lane ops in loop.
__global__ __launch_bounds__(256) void k_gat_agg(const unsigned short* __restrict__ t,
                          const int* __restrict__ adj, const int* __restrict__ cnt,
                          const float* __restrict__ als, const float* __restrict__ ald,
                          const float* __restrict__ b, unsigned short* __restrict__ h, int n){
  int lane = threadIdx.x & 63;
  int v = blockIdx.x*4 + uwave();
  if (v >= n) return;                         // uniform
  int c = min(cnt[v], CAP);
  const int* row = adj + (size_t)v*CAP;       // uniform base
  int ureg = v;                               // per-lane neighbor (softmax phase)
  if (lane < c) ureg = row[lane];
  float adv = ald[v];                         // uniform
  float e = als[ureg] + adv;                  // random 4B gather (L2-hot, 400KB)
  e = e > 0.f ? e : 0.2f*e;
  float es = als[v] + adv; es = es > 0.f ? es : 0.2f*es;
  float em = (lane < c) ? e : -1e30f;
  #pragma unroll
  for (int off = 32; off; off >>= 1) em = fmaxf(em, __shfl_xor(em, off));
  em = fmaxf(em, es);
  float p = (lane < c) ? __expf(e - em) : 0.f;
  float sm = p;
  #pragma unroll
  for (int off = 32; off; off >>= 1) sm += __shfl_xor(sm, off);
  float ps = __expf(es - em);
  float inv = 1.f / (sm + ps);
  float acc = ps * bfu(t[(size_t)v*64 + lane]);   // self row
  int j = 0;
  for (; j + 3 < c; j += 4){
    int u0 = row[j], u1 = row[j+1], u2 = row[j+2], u3 = row[j+3];  // s_load_dwordx4
    float a0 = als[u0], a1 = als[u1], a2 = als[u2], a3 = als[u3];  // uniform loads
    float x0 = bfu(t[(size_t)u0*64 + lane]);  // 4x 128B loads in flight
    float x1 = bfu(t[(size_t)u1*64 + lane]);
    float x2 = bfu(t[(size_t)u2*64 + lane]);
    float x3 = bfu(t[(size_t)u3*64 + lane]);
    float e0 = a0 + adv; e0 = e0 > 0.f ? e0 : 0.2f*e0;
    float e1 = a1 + adv; e1 = e1 > 0.f ? e1 : 0.2f*e1;
    float e2 = a2 + adv; e2 = e2 > 0.f ? e2 : 0.2f*e2;
    float e3 = a3 + adv; e3 = e3 > 0.f ? e3 : 0.2f*e3;
    acc = fmaf(__expf(e0 - em), x0, acc);
    acc = fmaf(__expf(e1 - em), x1, acc);
    acc = fmaf(__expf(e2 - em), x2, acc);
    acc = fmaf(__expf(e3 - em), x3, acc);
  }
  for (; j < c; j++){
    int u0 = row[j];
    float a0 = als[u0];
    float x0 = bfu(t[(size_t)u0*64 + lane]);
    float e0 = a0 + adv; e0 = e0 > 0.f ? e0 : 0.2f*e0;
    acc = fmaf(__expf(e0 - em), x0, acc);
  }
  float out = fmaxf(fmaf(acc, inv, b[lane]), 0.f);
  h[(size_t)v*64 + lane] = f2bf(out);         // 128B coalesced
}

// heads: gemm_alpha-mirror structure (dense Wcat/bcat, resident wreg[64]), bf16 h.
__global__ __launch_bounds__(256, 4) void k_heads(const unsigned short* __restrict__ h,
                        const float* __restrict__ Wcat, const float* __restrict__ bcat,
                        const float* __restrict__ Wb2, const float* __restrict__ bb2,
                        float* __restrict__ out_opt, float* __restrict__ out_bot, int n){
  int lane = threadIdx.x & 63;
  int gw = blockIdx.x*4 + uwave();
  int nw = gridDim.x*4;
  float wreg[64];
  #pragma unroll
  for (int k = 0; k < 64; k++) wreg[k] = Wcat[k*64 + lane];
  float bcr  = bcat[lane];
  float wb2r = (lane >= 32) ? Wb2[lane-32] : 0.f;
  float bb2r = bb2[0];
  for (int v = gw; v < n; v += nw){
    const uint4* xr = (const uint4*)(h + (size_t)v*64);   // uniform row, 8x16B
    float acc = bcr;
    #pragma unroll
    for (int k8 = 0; k8 < 8; k8++){
      uint4 c = xr[k8];
      acc = fmaf(bfl(c.x), wreg[k8*8+0], acc);
      acc = fmaf(bfh(c.x), wreg[k8*8+1], acc);
      acc = fmaf(bfl(c.y), wreg[k8*8+2], acc);
      acc = fmaf(bfh(c.y), wreg[k8*8+3], acc);
      acc = fmaf(bfl(c.z), wreg[k8*8+4], acc);
      acc = fmaf(bfh(c.z), wreg[k8*8+5], acc);
      acc = fmaf(bfl(c.w), wreg[k8*8+6], acc);
      acc = fmaf(bfh(c.w), wreg[k8*8+7], acc);
    }
    if (lane < 10) out_opt[(size_t)v*10 + lane] = acc;
    float contrib = fmaxf(acc, 0.f) * wb2r;   // 0 for lanes<32
    #pragma unroll
    for (int off = 32; off; off >>= 1) contrib += __shfl_xor(contrib, off);
    if (lane == 0) out_bot[v] = 1.f / (1.f + __expf(-(contrib + bb2r)));
  }
}

// mean embedding partials over bf16 h: block-reduce, 64-addr atomics
__global__ __launch_bounds__(256) void k_mean(const unsigned short* __restrict__ h,
                       float* __restrict__ emb_acc, int n){
  __shared__ float red[256];
  int tid = threadIdx.x;
  int w = tid >> 6, lane = tid & 63;
  float s = 0.f;
  for (int r = blockIdx.x*4 + w; r < n; r += 1024)
    s += __uint_as_float(((unsigned)h[(size_t)r*64 + lane]) << 16);
  red[tid] = s;
  __syncthreads();
  if (tid < 64)
    atomicAdd(&emb_acc[tid], red[tid] + red[64+tid] + red[128+tid] + red[192+tid]);
}

__global__ void k_embed(const float* __restrict__ emb_acc, float* __restrict__ out_emb,
                        float invn){
  if (threadIdx.x < 64) out_emb[threadIdx.x] = emb_acc[threadIdx.x] * invn;
}

extern "C" void kernel_launch(void* const* d_in, const int* in_sizes, int n_in,
                              void* d_out, int out_size, void* d_ws, size_t ws_size,
                              hipStream_t stream) {
  const float* x    = (const float*)d_in[0];
  const int*   ei   = (const int*)d_in[1];
  const float* W1   = (const float*)d_in[2];
  const float* b1   = (const float*)d_in[3];
  const float* W2   = (const float*)d_in[4];
  const float* a_s  = (const float*)d_in[5];
  const float* a_d  = (const float*)d_in[6];
  const float* b2   = (const float*)d_in[7];
  const float* W3   = (const float*)d_in[8];
  const float* b3   = (const float*)d_in[9];
  const float* Wopt = (const float*)d_in[10];
  const float* bopt = (const float*)d_in[11];
  const float* Wb1  = (const float*)d_in[12];
  const float* bb1  = (const float*)d_in[13];
  const float* Wb2  = (const float*)d_in[14];
  const float* bb2  = (const float*)d_in[15];

  int n = in_sizes[0] / 32;      // 100000
  int e = in_sizes[1] / 2;       // 1250000
  const int* src = ei;
  const int* dst = ei + e;

  char* ws = (char*)d_ws;
  size_t off = 0;
  auto alloc = [&](size_t bytes) -> void* {
    void* p = ws + off;
    off += (bytes + 255) & ~(size_t)255;
    return p;
  };
  int nb2 = (n + NP2 - 1) >> 7;  // 782 buckets
  int*            cnt     = (int*)           alloc((size_t)n * 4);
  int*            adj     = (int*)           alloc((size_t)n * CAP * 4);
  float*          als     = (float*)         alloc((size_t)n * 4);
  float*          ald     = (float*)         alloc((size_t)n * 4);
  unsigned short* xh      = (unsigned short*)alloc((size_t)(n+1) * 32 * 2); // +zero row
  unsigned short* tb      = (unsigned short*)alloc((size_t)(n+1) * 64 * 2); // +zero row
  unsigned short* hbuf    = (unsigned short*)alloc((size_t)n * 64 * 2);     // bf16 h
  float*          emb_acc = (float*)         alloc((size_t)64 * 4);
  float*          Wcat    = (float*)         alloc((size_t)4096 * 4);
  float*          bcat    = (float*)         alloc((size_t)64 * 4);
  int*            bcnt    = (int*)           alloc((size_t)nb2 * 4);

  // pairs buffer overlays hbuf (pairs consumed by k_fill before k_agg32g writes hbuf)
  int pbcap = e / nb2 + 384;     // mean + ~9 sigma (Binomial per-bucket count)
  long pcap_max = ((long)n * 128) / ((long)nb2 * 8);
  if (pbcap > (int)pcap_max) pbcap = (int)pcap_max;
  uint2* pairs = (uint2*)hbuf;

  float* out_opt = (float*)d_out;
  float* out_bot = out_opt + (size_t)n * 10;
  float* out_emb = out_bot + n;

  int nb8    = (n + 7) / 8;
  int nb4    = (n + 3) / 4;
  int nbN    = (n + 255) / 256;
  int nbP    = (e + 2047) / 2048;  // k_part: 2048 edges/block
  int total4 = n*32/4;
  int nbC    = (total4 + 255) / 256;

  k_setup<<<nbN, 256, 0, stream>>>(Wopt, bopt, Wb1, bb1, Wcat, bcat,
                                   bcnt, tb, xh, emb_acc, n, nb2);
  k_part<<<nbP, 256, 0, stream>>>(src, dst, pairs, bcnt, e, nb2, pbcap);
  k_fill<<<nb2, 256, 0, stream>>>(pairs, bcnt, cnt, adj, pbcap, n);
  k_castscale<<<nbC, 256, 0, stream>>>(x, cnt, xh, total4);

  // layer 1: GCN(32->64) fully fused: dual-node gather + epilogue gemm -> h1 (bf16)
  k_agg32g<<<nb8, 256, 0, stream>>>(xh, adj, cnt, W1, b1, hbuf, n);

  // layer 2: GAT(64->64): gemm -> bf16 t2 + scores, node-per-wave softmax-gather -> h2
  k_gemm_alpha<<<1024, 256, 0, stream>>>(hbuf, W2, a_s, a_d, tb, als, ald, n);
  k_gat_agg<<<nb4, 256, 0, stream>>>(tb, adj, cnt, als, ald, b2, hbuf, n);

  // layer 3: GCN(64->64): gemm (pre-scaled) -> bf16 t3, node-per-wave gather -> h3
  k_gemm_b<true><<<1024, 256, 0, stream>>>(hbuf, W3, cnt, tb, n);
  k_gcn_agg<<<nb4, 256, 0, stream>>>(tb, adj, cnt, b3, hbuf, n);

  // heads, mean, final scale
  k_heads<<<1024, 256, 0, stream>>>(hbuf, Wcat, bcat, Wb2, bb2,
                                    out_opt, out_bot, n);
  k_mean<<<256, 256, 0, stream>>>(hbuf, emb_acc, n);
  k_embed<<<1, 64, 0, stream>>>(emb_acc, out_emb, 1.0f / (float)n);
}

// Round 7
// 349.343 us; speedup vs baseline: 1.0737x; 1.0737x over previous
//
#include <hip/hip_runtime.h>
#include <hip/hip_bf16.h>

// WorkflowGNN: GCN(32->64)+ReLU, GAT(64->64,h=1)+ReLU, GCN(64->64)+ReLU,
// heads: opt [N,10], bottleneck [N,1], mean-embed [64]. f32 in/out.
// R22: aggs = 8 NODES PER WAVE (8-lane group per node, lane q = feats q*8..+7).
// Keeps the 1KB uint4 gather geometry (R21b's 128B loads were the regression)
// but group-private accumulators -> NO butterfly (was ~2 DS + 2 VALU per edge).
// u broadcast = 1 shfl/iter; GAT w recomputed from als[u] in-loop; softmax via
// 3-level intra-group shfl_xor. k_fill inits adj slots to n (zero row) so the
// hot loop needs no masks; als[n]=0. Store = contiguous 1KB uint4 (8 rows).
// R20 (kept): k_agg32g epilogue via constant-index v_readlane.
// R19 (kept): atomic-free adjacency build (k_part exact buckets + k_fill LDS).

#define CAP 64
#define NP2 128          // nodes per bucket (LDS tile rows), = 1<<7
#define NB2MAX 800       // LDS cursor array bound (n <= 102400)

__device__ __forceinline__ int uwave(){                 // wave id, known-uniform
  return __builtin_amdgcn_readfirstlane(threadIdx.x >> 6);
}
__device__ __forceinline__ unsigned short f2bf(float f){ // RNE, finite inputs
  unsigned u = __float_as_uint(f);
  return (unsigned short)((u + 0x7fffu + ((u >> 16) & 1u)) >> 16);
}
__device__ __forceinline__ float bfl(unsigned u){ return __uint_as_float(u << 16); }
__device__ __forceinline__ float bfh(unsigned u){ return __uint_as_float(u & 0xffff0000u); }
__device__ __forceinline__ float bfu(unsigned short s){ return __uint_as_float(((unsigned)s) << 16); }
__device__ __forceinline__ float rdlane(float v, int l){ // constant-lane broadcast
  return __uint_as_float(__builtin_amdgcn_readlane(__float_as_uint(v), l));
}

// setup: zero bcnt/pad-rows/emb_acc/als[n], pack Wcat/bcat
__global__ void k_setup(const float* __restrict__ Wopt, const float* __restrict__ bopt,
                        const float* __restrict__ Wb1, const float* __restrict__ bb1,
                        float* __restrict__ Wcat, float* __restrict__ bcat,
                        int* __restrict__ bcnt, unsigned short* __restrict__ tb,
                        unsigned short* __restrict__ xh, float* __restrict__ emb_acc,
                        float* __restrict__ als, int n, int nb2){
  int i = blockIdx.x*blockDim.x + threadIdx.x;
  if (i < nb2) bcnt[i] = 0;
  if (blockIdx.x == 0){
    int tid = threadIdx.x;
    for (int j = tid; j < 4096; j += 256){    // pack head weights
      int f = j >> 6, c = j & 63;
      float w = 0.f;
      if (c < 10)       w = Wopt[f*10 + c];
      else if (c >= 32) w = Wb1[f*32 + (c-32)];
      Wcat[j] = w;
    }
    if (tid < 64){
      float b = 0.f;
      if (tid < 10)       b = bopt[tid];
      else if (tid >= 32) b = bb1[tid-32];
      bcat[tid] = b;
      tb[(size_t)n*64 + tid] = 0;             // zero pad row (64-feat)
      emb_acc[tid] = 0.f;
      if (tid == 0) als[n] = 0.f;             // pad score
    }
    if (tid >= 64 && tid < 96) xh[(size_t)n*32 + (tid-64)] = 0;  // zero pad row (32-feat)
  }
}

// pass A: bin edges into exact dst-range buckets (bk = dst>>7). One coalesced
// read of src/dst, LDS-aggregated cursors -> ~nb2 global atomics per block.
__global__ __launch_bounds__(256) void k_part(const int* __restrict__ src,
                        const int* __restrict__ dst,
                        uint2* __restrict__ pairs, int* __restrict__ bcnt,
                        int e, int nb2, int pbcap){
  __shared__ int lcnt[NB2MAX];
  __shared__ int lbase[NB2MAX];
  int tid = threadIdx.x;
  for (int j = tid; j < nb2; j += 256) lcnt[j] = 0;
  __syncthreads();
  int i0 = blockIdx.x*2048 + tid*8;
  int d[8], s[8], bk[8], lp[8];
  int nv = e - i0;
  if (nv > 8) nv = 8;
  if (nv < 0) nv = 0;
  if (nv == 8){
    int4 d0 = *(const int4*)(dst + i0), d1 = *(const int4*)(dst + i0 + 4);
    int4 s0 = *(const int4*)(src + i0), s1 = *(const int4*)(src + i0 + 4);
    d[0]=d0.x; d[1]=d0.y; d[2]=d0.z; d[3]=d0.w;
    d[4]=d1.x; d[5]=d1.y; d[6]=d1.z; d[7]=d1.w;
    s[0]=s0.x; s[1]=s0.y; s[2]=s0.z; s[3]=s0.w;
    s[4]=s1.x; s[5]=s1.y; s[6]=s1.z; s[7]=s1.w;
  } else {
    #pragma unroll
    for (int j = 0; j < 8; j++){ d[j] = 0; s[j] = 0; }
    for (int j = 0; j < nv; j++){ d[j] = dst[i0+j]; s[j] = src[i0+j]; }
  }
  #pragma unroll
  for (int j = 0; j < 8; j++){
    if (j < nv){
      bk[j] = d[j] >> 7;                      // exact: bucket owns [bk*128, bk*128+128)
      lp[j] = atomicAdd(&lcnt[bk[j]], 1);
    }
  }
  __syncthreads();
  for (int j = tid; j < nb2; j += 256){
    int c = lcnt[j];
    if (c) lbase[j] = atomicAdd(&bcnt[j], c);
  }
  __syncthreads();
  #pragma unroll
  for (int j = 0; j < 8; j++){
    if (j < nv){
      int p = lbase[bk[j]] + lp[j];
      if (p < pbcap)
        pairs[(size_t)bk[j]*pbcap + p] = make_uint2((unsigned)d[j], (unsigned)s[j]);
    }
  }
}

// pass B: one block per bucket. adj rows built in LDS (LDS atomics only),
// slots pre-initialized to n (zero-row index) -> downstream gathers need no
// masks. Rows + cnt written fully coalesced.
__global__ __launch_bounds__(256) void k_fill(const uint2* __restrict__ pairs,
                        const int* __restrict__ bcnt, int* __restrict__ cnt,
                        int* __restrict__ adj, int pbcap, int n){
  __shared__ int lc[NP2];
  __shared__ int ladj[NP2*CAP];               // 32KB
  int b = blockIdx.x;
  int lo = b << 7;
  int nn = min(NP2, n - lo);
  int tid = threadIdx.x;
  for (int j = tid; j < NP2; j += 256) lc[j] = 0;
  int4 nfill = make_int4(n, n, n, n);
  for (int j = tid; j < NP2*CAP/4; j += 256) ((int4*)ladj)[j] = nfill;
  __syncthreads();
  int m = bcnt[b];
  if (m > pbcap) m = pbcap;
  const uint2* pb = pairs + (size_t)b*pbcap;
  for (int j = tid; j < m; j += 256){
    uint2 p = pb[j];
    int r = (int)p.x - lo;
    int pos = atomicAdd(&lc[r], 1);
    if (pos < CAP) ladj[(r << 6) + pos] = (int)p.y;
  }
  __syncthreads();
  if (tid < nn) cnt[lo + tid] = lc[tid];
  int tot = nn << 4;                          // nn*64 ints / 4 per uint4
  uint4* ga = (uint4*)(adj + (size_t)lo*CAP);
  const uint4* la = (const uint4*)ladj;
  for (int j = tid; j < tot; j += 256) ga[j] = la[j];
}

// cast x -> bf16, pre-scaled by rsqrt(deg): xs[v] = x[v]*rsqrt(cnt[v]+1)
__global__ void k_castscale(const float* __restrict__ x, const int* __restrict__ cnt,
                            unsigned short* __restrict__ xh, int total4){
  int i = blockIdx.x*blockDim.x + threadIdx.x;
  if (i >= total4) return;
  int row = i >> 3;                           // 8 float4 per 32-elem row
  float dv = rsqrtf((float)(cnt[row] + 1));
  float4 v = ((const float4*)x)[i];
  uint2 o;
  o.x = (unsigned)f2bf(v.x*dv) | ((unsigned)f2bf(v.y*dv) << 16);
  o.y = (unsigned)f2bf(v.z*dv) | ((unsigned)f2bf(v.w*dv) << 16);
  ((uint2*)xh)[i] = o;
}

// layer-1 FUSED aggregate+gemm, DUAL-NODE, bf16 out (R20 structure).
__global__ __launch_bounds__(256) void k_agg32g(const unsigned short* __restrict__ xh,
                          const int* __restrict__ adj, const int* __restrict__ cnt,
                          const float* __restrict__ W1, const float* __restrict__ b1,
                          unsigned short* __restrict__ h, int n){
  int lane = threadIdx.x & 63;
  float wreg[32];
  #pragma unroll
  for (int k = 0; k < 32; k++) wreg[k] = W1[k*64 + lane];  // coalesced, once
  float br = b1[lane];
  int v0 = blockIdx.x*8 + uwave()*2;
  if (v0 >= n) return;                        // uniform
  int v1 = v0 + 1;
  bool has1 = v1 < n;
  if (!has1) v1 = v0;
  int cn0 = cnt[v0], cn1 = cnt[v1];
  int c0 = min(cn0, CAP), c1 = min(cn1, CAP);
  int ureg0 = n, ureg1 = n;                   // pad -> zero row
  if (lane < c0) ureg0 = (adj + (size_t)v0*CAP)[lane];
  if (lane < c1) ureg1 = (adj + (size_t)v1*CAP)[lane];
  int g = lane >> 3, q = lane & 7;
  float4 a0 = {0.f,0.f,0.f,0.f}, a1 = {0.f,0.f,0.f,0.f};
  int itm = (max(c0, c1) + 7) >> 3;
  #pragma unroll 2
  for (int jj = 0; jj < itm; jj++){
    int u0 = __shfl(ureg0, jj*8 + g);         // pad iters -> zero row (L1-hot)
    int u1 = __shfl(ureg1, jj*8 + g);
    uint2 r0 = ((const uint2*)(xh + (size_t)u0*32))[q];   // both loads in flight
    uint2 r1 = ((const uint2*)(xh + (size_t)u1*32))[q];
    a0.x += bfl(r0.x); a0.y += bfh(r0.x); a0.z += bfl(r0.y); a0.w += bfh(r0.y);
    a1.x += bfl(r1.x); a1.y += bfh(r1.x); a1.z += bfl(r1.y); a1.w += bfh(r1.y);
  }
  #pragma unroll
  for (int off = 8; off <= 32; off <<= 1){
    a0.x += __shfl_xor(a0.x, off); a0.y += __shfl_xor(a0.y, off);
    a0.z += __shfl_xor(a0.z, off); a0.w += __shfl_xor(a0.w, off);
    a1.x += __shfl_xor(a1.x, off); a1.y += __shfl_xor(a1.y, off);
    a1.z += __shfl_xor(a1.z, off); a1.w += __shfl_xor(a1.w, off);
  }
  uint2 s0 = ((const uint2*)(xh + (size_t)v0*32))[q];     // self rows (pre-scaled)
  uint2 s1 = ((const uint2*)(xh + (size_t)v1*32))[q];
  a0.x += bfl(s0.x); a0.y += bfh(s0.x); a0.z += bfl(s0.y); a0.w += bfh(s0.y);
  a1.x += bfl(s1.x); a1.y += bfh(s1.x); a1.z += bfl(s1.y); a1.w += bfh(s1.y);
  float dv0 = rsqrtf((float)(cn0 + 1)), dv1 = rsqrtf((float)(cn1 + 1));
  a0.x *= dv0; a0.y *= dv0; a0.z *= dv0; a0.w *= dv0;
  a1.x *= dv1; a1.y *= dv1; a1.z *= dv1; a1.w *= dv1;
  float h0 = br, h1v = br;                    // epilogue gemms via v_readlane (VALU)
  #pragma unroll
  for (int q2 = 0; q2 < 8; q2++){
    float w0x = rdlane(a0.x, q2), w1x = rdlane(a1.x, q2);
    float w0y = rdlane(a0.y, q2), w1y = rdlane(a1.y, q2);
    float w0z = rdlane(a0.z, q2), w1z = rdlane(a1.z, q2);
    float w0w = rdlane(a0.w, q2), w1w = rdlane(a1.w, q2);
    h0 = fmaf(w0x, wreg[q2*4+0], h0); h1v = fmaf(w1x, wreg[q2*4+0], h1v);
    h0 = fmaf(w0y, wreg[q2*4+1], h0); h1v = fmaf(w1y, wreg[q2*4+1], h1v);
    h0 = fmaf(w0z, wreg[q2*4+2], h0); h1v = fmaf(w1z, wreg[q2*4+2], h1v);
    h0 = fmaf(w0w, wreg[q2*4+3], h0); h1v = fmaf(w1w, wreg[q2*4+3], h1v);
  }
  h[(size_t)v0*64 + lane] = f2bf(fmaxf(h0, 0.f));   // 128B coalesced
  if (has1) h[(size_t)v1*64 + lane] = f2bf(fmaxf(h1v, 0.f));
}

// K=64 GEMM (bf16 in) -> bf16 out, optional pre-scale by rsqrt(deg)
template<bool SCALE>
__global__ __launch_bounds__(256, 4) void k_gemm_b(const unsigned short* __restrict__ x,
                       const float* __restrict__ W, const int* __restrict__ cnt,
                       unsigned short* __restrict__ t, int n){
  int lane = threadIdx.x & 63;
  int gw = blockIdx.x*4 + uwave();
  int nw = gridDim.x*4;
  float wreg[64];
  #pragma unroll
  for (int k = 0; k < 64; k++) wreg[k] = W[k*64 + lane];
  for (int v = gw; v < n; v += nw){
    const uint4* xr = (const uint4*)(x + (size_t)v*64);   // uniform row, 8x16B
    float acc = 0.f;
    #pragma unroll
    for (int k8 = 0; k8 < 8; k8++){
      uint4 c = xr[k8];
      acc = fmaf(bfl(c.x), wreg[k8*8+0], acc);
      acc = fmaf(bfh(c.x), wreg[k8*8+1], acc);
      acc = fmaf(bfl(c.y), wreg[k8*8+2], acc);
      acc = fmaf(bfh(c.y), wreg[k8*8+3], acc);
      acc = fmaf(bfl(c.z), wreg[k8*8+4], acc);
      acc = fmaf(bfh(c.z), wreg[k8*8+5], acc);
      acc = fmaf(bfl(c.w), wreg[k8*8+6], acc);
      acc = fmaf(bfh(c.w), wreg[k8*8+7], acc);
    }
    if (SCALE) acc *= rsqrtf((float)(cnt[v] + 1));
    t[(size_t)v*64 + lane] = f2bf(acc);                    // 128B coalesced
  }
}

// K=64 GEMM (bf16 in) -> bf16 out + fused alpha_src/alpha_dst dots (f32 scores)
__global__ __launch_bounds__(256, 4) void k_gemm_alpha(const unsigned short* __restrict__ x,
                       const float* __restrict__ W,
                       const float* __restrict__ asrc, const float* __restrict__ adst,
                       unsigned short* __restrict__ t, float* __restrict__ als,
                       float* __restrict__ ald, int n){
  int lane = threadIdx.x & 63;
  int gw = blockIdx.x*4 + uwave();
  int nw = gridDim.x*4;
  float wreg[64];
  #pragma unroll
  for (int k = 0; k < 64; k++) wreg[k] = W[k*64 + lane];
  float asr = asrc[lane], adr = adst[lane];
  for (int v = gw; v < n; v += nw){
    const uint4* xr = (const uint4*)(x + (size_t)v*64);
    float acc = 0.f;
    #pragma unroll
    for (int k8 = 0; k8 < 8; k8++){
      uint4 c = xr[k8];
      acc = fmaf(bfl(c.x), wreg[k8*8+0], acc);
      acc = fmaf(bfh(c.x), wreg[k8*8+1], acc);
      acc = fmaf(bfl(c.y), wreg[k8*8+2], acc);
      acc = fmaf(bfh(c.y), wreg[k8*8+3], acc);
      acc = fmaf(bfl(c.z), wreg[k8*8+4], acc);
      acc = fmaf(bfh(c.z), wreg[k8*8+5], acc);
      acc = fmaf(bfl(c.w), wreg[k8*8+6], acc);
      acc = fmaf(bfh(c.w), wreg[k8*8+7], acc);
    }
    t[(size_t)v*64 + lane] = f2bf(acc);
    float s1 = acc * asr, s2 = acc * adr;
    #pragma unroll
    for (int off = 32; off; off >>= 1){
      s1 += __shfl_xor(s1, off);
      s2 += __shfl_xor(s2, off);
    }
    if (lane == 0){ als[v] = s1; ald[v] = s2; }
  }
}

// GCN agg (layer 3): 8 NODES/WAVE. Group g (8 lanes) owns node v0+g; lane q
// holds feats q*8..q*8+7. Per iter: 1 shfl u-broadcast + 1KB uint4 load.
// No butterfly; epilogue store = contiguous 1KB.
__global__ __launch_bounds__(256) void k_gcn_agg(const unsigned short* __restrict__ t,
                          const int* __restrict__ adj, const int* __restrict__ cnt,
                          const float* __restrict__ b, unsigned short* __restrict__ h, int n){
  int lane = threadIdx.x & 63;
  int g = lane >> 3, q = lane & 7;
  int v0 = blockIdx.x*32 + uwave()*8;
  if (v0 >= n) return;                        // uniform
  int vg = v0 + g;
  bool vok = vg < n;
  int vgc = vok ? vg : n - 1;                 // clamp for loads only
  int cn = cnt[vgc];
  int c = vok ? min(cn, CAP) : 0;
  int cm = c;                                 // wave max degree (groups differ)
  cm = max(cm, __shfl_xor(cm, 8));
  cm = max(cm, __shfl_xor(cm, 16));
  cm = max(cm, __shfl_xor(cm, 32));
  int cmax = __builtin_amdgcn_readfirstlane(cm);
  const int* arow = adj + (size_t)vgc*CAP;    // per-lane base
  float a[8] = {0,0,0,0,0,0,0,0};
  int bsel = (lane & 56);
  for (int blk = 0; blk*8 < cmax; blk++){
    int ureg = arow[blk*8 + q];               // 8 slots of own row (pad slots = n)
    #pragma unroll
    for (int j2 = 0; j2 < 8; j2++){
      if (blk*8 + j2 >= cmax) break;          // uniform
      int u = __shfl(ureg, bsel | j2);        // group-slot broadcast
      uint4 r = ((const uint4*)(t + (size_t)u*64))[q];    // 1KB wave load
      a[0] += bfl(r.x); a[1] += bfh(r.x); a[2] += bfl(r.y); a[3] += bfh(r.y);
      a[4] += bfl(r.z); a[5] += bfh(r.z); a[6] += bfl(r.w); a[7] += bfh(r.w);
    }
  }
  uint4 s = ((const uint4*)(t + (size_t)vgc*64))[q];      // self row
  a[0] += bfl(s.x); a[1] += bfh(s.x); a[2] += bfl(s.y); a[3] += bfh(s.y);
  a[4] += bfl(s.z); a[5] += bfh(s.z); a[6] += bfl(s.w); a[7] += bfh(s.w);
  float dv = rsqrtf((float)(cn + 1));
  float4 b0 = ((const float4*)b)[2*q], b1v = ((const float4*)b)[2*q+1];
  float r0 = fmaxf(fmaf(a[0], dv, b0.x), 0.f),  r1 = fmaxf(fmaf(a[1], dv, b0.y), 0.f);
  float r2 = fmaxf(fmaf(a[2], dv, b0.z), 0.f),  r3 = fmaxf(fmaf(a[3], dv, b0.w), 0.f);
  float r4 = fmaxf(fmaf(a[4], dv, b1v.x), 0.f), r5 = fmaxf(fmaf(a[5], dv, b1v.y), 0.f);
  float r6 = fmaxf(fmaf(a[6], dv, b1v.z), 0.f), r7 = fmaxf(fmaf(a[7], dv, b1v.w), 0.f);
  uint4 o;
  o.x = (unsigned)f2bf(r0) | ((unsigned)f2bf(r1) << 16);
  o.y = (unsigned)f2bf(r2) | ((unsigned)f2bf(r3) << 16);
  o.z = (unsigned)f2bf(r4) | ((unsigned)f2bf(r5) << 16);
  o.w = (unsigned)f2bf(r6) | ((unsigned)f2bf(r7) << 16);
  if (vok) ((uint4*)(h + (size_t)vg*64))[q] = o;          // contiguous 1KB store
}

// GAT agg: 8 NODES/WAVE. Softmax over own row's scores (per-lane slot gather,
// 3-level intra-group shfl_xor); gather loop recomputes w from als[u]
// (bit-identical ops). Pad slots -> u=n: als[n]=0, zero row -> 0 contribution.
__global__ __launch_bounds__(256) void k_gat_agg(const unsigned short* __restrict__ t,
                          const int* __restrict__ adj, const int* __restrict__ cnt,
                          const float* __restrict__ als, const float* __restrict__ ald,
                          const float* __restrict__ b, unsigned short* __restrict__ h, int n){
  int lane = threadIdx.x & 63;
  int g = lane >> 3, q = lane & 7;
  int v0 = blockIdx.x*32 + uwave()*8;
  if (v0 >= n) return;                        // uniform
  int vg = v0 + g;
  bool vok = vg < n;
  int vgc = vok ? vg : n - 1;
  int c = vok ? min(cnt[vgc], CAP) : 0;
  int cm = c;
  cm = max(cm, __shfl_xor(cm, 8));
  cm = max(cm, __shfl_xor(cm, 16));
  cm = max(cm, __shfl_xor(cm, 32));
  int cmax = __builtin_amdgcn_readfirstlane(cm);
  const int* arow = adj + (size_t)vgc*CAP;
  float adv = ald[vgc];
  float es = als[vgc] + adv; es = es > 0.f ? es : 0.2f*es;
  // softmax phase: per-lane slots q, q+8, ... (masked), intra-group reduce
  float er[8];
  float em = es;
  #pragma unroll
  for (int r = 0; r < 8; r++){
    if (r*8 >= cmax) break;                   // uniform
    int slot = r*8 + q;
    int u = arow[slot];                       // pad slot -> n (als[n]=0)
    float ev = als[u] + adv; ev = ev > 0.f ? ev : 0.2f*ev;
    er[r] = (slot < c) ? ev : -1e30f;
    em = fmaxf(em, er[r]);
  }
  em = fmaxf(em, __shfl_xor(em, 1));
  em = fmaxf(em, __shfl_xor(em, 2));
  em = fmaxf(em, __shfl_xor(em, 4));
  float sm = 0.f;
  #pragma unroll
  for (int r = 0; r < 8; r++){
    if (r*8 >= cmax) break;
    sm += ((r*8 + q) < c) ? __expf(er[r] - em) : 0.f;
  }
  sm += __shfl_xor(sm, 1);
  sm += __shfl_xor(sm, 2);
  sm += __shfl_xor(sm, 4);
  float ps = __expf(es - em);
  float inv = 1.f / (sm + ps);
  // gather: w recomputed from als[u] (same ops as er -> bit-identical)
  float a[8] = {0,0,0,0,0,0,0,0};
  int bsel = (lane & 56);
  for (int blk = 0; blk*8 < cmax; blk++){
    int ureg = arow[blk*8 + q];
    #pragma unroll
    for (int j2 = 0; j2 < 8; j2++){
      if (blk*8 + j2 >= cmax) break;          // uniform
      int u = __shfl(ureg, bsel | j2);
      float ev = als[u] + adv; ev = ev > 0.f ? ev : 0.2f*ev;
      float w = __expf(ev - em);              // pad: u=n -> w*0-row = 0 anyway
      uint4 r = ((const uint4*)(t + (size_t)u*64))[q];    // 1KB wave load
      a[0] = fmaf(w, bfl(r.x), a[0]); a[1] = fmaf(w, bfh(r.x), a[1]);
      a[2] = fmaf(w, bfl(r.y), a[2]); a[3] = fmaf(w, bfh(r.y), a[3]);
      a[4] = fmaf(w, bfl(r.z), a[4]); a[5] = fmaf(w, bfh(r.z), a[5]);
      a[6] = fmaf(w, bfl(r.w), a[6]); a[7] = fmaf(w, bfh(r.w), a[7]);
    }
  }
  uint4 s = ((const uint4*)(t + (size_t)vgc*64))[q];      // self row
  a[0] = fmaf(ps, bfl(s.x), a[0]); a[1] = fmaf(ps, bfh(s.x), a[1]);
  a[2] = fmaf(ps, bfl(s.y), a[2]); a[3] = fmaf(ps, bfh(s.y), a[3]);
  a[4] = fmaf(ps, bfl(s.z), a[4]); a[5] = fmaf(ps, bfh(s.z), a[5]);
  a[6] = fmaf(ps, bfl(s.w), a[6]); a[7] = fmaf(ps, bfh(s.w), a[7]);
  float4 b0 = ((const float4*)b)[2*q], b1v = ((const float4*)b)[2*q+1];
  float r0 = fmaxf(fmaf(a[0], inv, b0.x), 0.f),  r1 = fmaxf(fmaf(a[1], inv, b0.y), 0.f);
  float r2 = fmaxf(fmaf(a[2], inv, b0.z), 0.f),  r3 = fmaxf(fmaf(a[3], inv, b0.w), 0.f);
  float r4 = fmaxf(fmaf(a[4], inv, b1v.x), 0.f), r5 = fmaxf(fmaf(a[5], inv, b1v.y), 0.f);
  float r6 = fmaxf(fmaf(a[6], inv, b1v.z), 0.f), r7 = fmaxf(fmaf(a[7], inv, b1v.w), 0.f);
  uint4 o;
  o.x = (unsigned)f2bf(r0) | ((unsigned)f2bf(r1) << 16);
  o.y = (unsigned)f2bf(r2) | ((unsigned)f2bf(r3) << 16);
  o.z = (unsigned)f2bf(r4) | ((unsigned)f2bf(r5) << 16);
  o.w = (unsigned)f2bf(r6) | ((unsigned)f2bf(r7) << 16);
  if (vok) ((uint4*)(h + (size_t)vg*64))[q] = o;          // contiguous 1KB store
}

// heads: gemm_alpha-mirror structure (dense Wcat/bcat, resident wreg[64]), bf16 h.
__global__ __launch_bounds__(256, 4) void k_heads(const unsigned short* __restrict__ h,
                        const float* __restrict__ Wcat, const float* __restrict__ bcat,
                        const float* __restrict__ Wb2, const float* __restrict__ bb2,
                        float* __restrict__ out_opt, float* __restrict__ out_bot, int n){
  int lane = threadIdx.x & 63;
  int gw = blockIdx.x*4 + uwave();
  int nw = gridDim.x*4;
  float wreg[64];
  #pragma unroll
  for (int k = 0; k < 64; k++) wreg[k] = Wcat[k*64 + lane];
  float bcr  = bcat[lane];
  float wb2r = (lane >= 32) ? Wb2[lane-32] : 0.f;
  float bb2r = bb2[0];
  for (int v = gw; v < n; v += nw){
    const uint4* xr = (const uint4*)(h + (size_t)v*64);   // uniform row, 8x16B
    float acc = bcr;
    #pragma unroll
    for (int k8 = 0; k8 < 8; k8++){
      uint4 c = xr[k8];
      acc = fmaf(bfl(c.x), wreg[k8*8+0], acc);
      acc = fmaf(bfh(c.x), wreg[k8*8+1], acc);
      acc = fmaf(bfl(c.y), wreg[k8*8+2], acc);
      acc = fmaf(bfh(c.y), wreg[k8*8+3], acc);
      acc = fmaf(bfl(c.z), wreg[k8*8+4], acc);
      acc = fmaf(bfh(c.z), wreg[k8*8+5], acc);
      acc = fmaf(bfl(c.w), wreg[k8*8+6], acc);
      acc = fmaf(bfh(c.w), wreg[k8*8+7], acc);
    }
    if (lane < 10) out_opt[(size_t)v*10 + lane] = acc;
    float contrib = fmaxf(acc, 0.f) * wb2r;   // 0 for lanes<32
    #pragma unroll
    for (int off = 32; off; off >>= 1) contrib += __shfl_xor(contrib, off);
    if (lane == 0) out_bot[v] = 1.f / (1.f + __expf(-(contrib + bb2r)));
  }
}

// mean embedding partials over bf16 h: block-reduce, 64-addr atomics
__global__ __launch_bounds__(256) void k_mean(const unsigned short* __restrict__ h,
                       float* __restrict__ emb_acc, int n){
  __shared__ float red[256];
  int tid = threadIdx.x;
  int w = tid >> 6, lane = tid & 63;
  float s = 0.f;
  for (int r = blockIdx.x*4 + w; r < n; r += 1024)
    s += __uint_as_float(((unsigned)h[(size_t)r*64 + lane]) << 16);
  red[tid] = s;
  __syncthreads();
  if (tid < 64)
    atomicAdd(&emb_acc[tid], red[tid] + red[64+tid] + red[128+tid] + red[192+tid]);
}

__global__ void k_embed(const float* __restrict__ emb_acc, float* __restrict__ out_emb,
                        float invn){
  if (threadIdx.x < 64) out_emb[threadIdx.x] = emb_acc[threadIdx.x] * invn;
}

extern "C" void kernel_launch(void* const* d_in, const int* in_sizes, int n_in,
                              void* d_out, int out_size, void* d_ws, size_t ws_size,
                              hipStream_t stream) {
  const float* x    = (const float*)d_in[0];
  const int*   ei   = (const int*)d_in[1];
  const float* W1   = (const float*)d_in[2];
  const float* b1   = (const float*)d_in[3];
  const float* W2   = (const float*)d_in[4];
  const float* a_s  = (const float*)d_in[5];
  const float* a_d  = (const float*)d_in[6];
  const float* b2   = (const float*)d_in[7];
  const float* W3   = (const float*)d_in[8];
  const float* b3   = (const float*)d_in[9];
  const float* Wopt = (const float*)d_in[10];
  const float* bopt = (const float*)d_in[11];
  const float* Wb1  = (const float*)d_in[12];
  const float* bb1  = (const float*)d_in[13];
  const float* Wb2  = (const float*)d_in[14];
  const float* bb2  = (const float*)d_in[15];

  int n = in_sizes[0] / 32;      // 100000
  int e = in_sizes[1] / 2;       // 1250000
  const int* src = ei;
  const int* dst = ei + e;

  char* ws = (char*)d_ws;
  size_t off = 0;
  auto alloc = [&](size_t bytes) -> void* {
    void* p = ws + off;
    off += (bytes + 255) & ~(size_t)255;
    return p;
  };
  int nb2 = (n + NP2 - 1) >> 7;  // 782 buckets
  int*            cnt     = (int*)           alloc((size_t)n * 4);
  int*            adj     = (int*)           alloc((size_t)n * CAP * 4);
  float*          als     = (float*)         alloc((size_t)(n+1) * 4);  // +pad score
  float*          ald     = (float*)         alloc((size_t)n * 4);
  unsigned short* xh      = (unsigned short*)alloc((size_t)(n+1) * 32 * 2); // +zero row
  unsigned short* tb      = (unsigned short*)alloc((size_t)(n+1) * 64 * 2); // +zero row
  unsigned short* hbuf    = (unsigned short*)alloc((size_t)n * 64 * 2);     // bf16 h
  float*          emb_acc = (float*)         alloc((size_t)64 * 4);
  float*          Wcat    = (float*)         alloc((size_t)4096 * 4);
  float*          bcat    = (float*)         alloc((size_t)64 * 4);
  int*            bcnt    = (int*)           alloc((size_t)nb2 * 4);

  // pairs buffer overlays hbuf (pairs consumed by k_fill before k_agg32g writes hbuf)
  int pbcap = e / nb2 + 384;     // mean + ~9 sigma (Binomial per-bucket count)
  long pcap_max = ((long)n * 128) / ((long)nb2 * 8);
  if (pbcap > (int)pcap_max) pbcap = (int)pcap_max;
  uint2* pairs = (uint2*)hbuf;

  float* out_opt = (float*)d_out;
  float* out_bot = out_opt + (size_t)n * 10;
  float* out_emb = out_bot + n;

  int nb8    = (n + 7) / 8;
  int nbW    = (n + 31) / 32;      // 8-node-per-wave aggs: 32 nodes/block
  int nbN    = (n + 255) / 256;
  int nbP    = (e + 2047) / 2048;  // k_part: 2048 edges/block
  int total4 = n*32/4;
  int nbC    = (total4 + 255) / 256;

  k_setup<<<nbN, 256, 0, stream>>>(Wopt, bopt, Wb1, bb1, Wcat, bcat,
                                   bcnt, tb, xh, emb_acc, als, n, nb2);
  k_part<<<nbP, 256, 0, stream>>>(src, dst, pairs, bcnt, e, nb2, pbcap);
  k_fill<<<nb2, 256, 0, stream>>>(pairs, bcnt, cnt, adj, pbcap, n);
  k_castscale<<<nbC, 256, 0, stream>>>(x, cnt, xh, total4);

  // layer 1: GCN(32->64) fully fused: dual-node gather + epilogue gemm -> h1 (bf16)
  k_agg32g<<<nb8, 256, 0, stream>>>(xh, adj, cnt, W1, b1, hbuf, n);

  // layer 2: GAT(64->64): gemm -> bf16 t2 + scores, 8-node/wave softmax-gather -> h2
  k_gemm_alpha<<<1024, 256, 0, stream>>>(hbuf, W2, a_s, a_d, tb, als, ald, n);
  k_gat_agg<<<nbW, 256, 0, stream>>>(tb, adj, cnt, als, ald, b2, hbuf, n);

  // layer 3: GCN(64->64): gemm (pre-scaled) -> bf16 t3, 8-node/wave gather -> h3
  k_gemm_b<true><<<1024, 256, 0, stream>>>(hbuf, W3, cnt, tb, n);
  k_gcn_agg<<<nbW, 256, 0, stream>>>(tb, adj, cnt, b3, hbuf, n);

  // heads, mean, final scale
  k_heads<<<1024, 256, 0, stream>>>(hbuf, Wcat, bcat, Wb2, bb2,
                                    out_opt, out_bot, n);
  k_mean<<<256, 256, 0, stream>>>(hbuf, emb_acc, n);
  k_embed<<<1, 64, 0, stream>>>(emb_acc, out_emb, 1.0f / (float)n);
}